// Round 5
// baseline (193.825 us; speedup 1.0000x reference)
//
#include <hip/hip_runtime.h>
#include <hip/hip_bf16.h>

#define NH 16
#define LQ 2048
#define SK 2048
#define QTILE 128
#define KVB 64
#define NSBLK (SK / KVB)           // 32
#define TILE_BYTES 16384           // K tile 8KB + V^T tile 8KB
#define WS_NEED ((size_t)4 * NH * NSBLK * TILE_BYTES)  // 32 MB
#define KSTR 72                    // fallback-kernel LDS stride

typedef __bf16 bf16_t;
typedef bf16_t bf16x8 __attribute__((ext_vector_type(8)));
typedef bf16_t bf16x2 __attribute__((ext_vector_type(2)));
typedef float f32x16 __attribute__((ext_vector_type(16)));
typedef float f32x4 __attribute__((ext_vector_type(4)));
typedef unsigned int uint2v __attribute__((ext_vector_type(2)));
typedef unsigned int uint4v __attribute__((ext_vector_type(4)));

union U4B8 { uint4v u; bf16x8 v; };

__device__ __forceinline__ bf16x8 cvt8v(f32x4 a, f32x4 b) {
  bf16x8 r;
  r[0]=(bf16_t)a[0]; r[1]=(bf16_t)a[1]; r[2]=(bf16_t)a[2]; r[3]=(bf16_t)a[3];
  r[4]=(bf16_t)b[0]; r[5]=(bf16_t)b[1]; r[6]=(bf16_t)b[2]; r[7]=(bf16_t)b[3];
  return r;
}
__device__ __forceinline__ unsigned pk2(float lo, float hi) {
  bf16x2 t; t[0] = (bf16_t)lo; t[1] = (bf16_t)hi;
  return __builtin_bit_cast(unsigned, t);
}
__device__ __forceinline__ void gll16(const void* g, void* l) {
  __builtin_amdgcn_global_load_lds(
      (const __attribute__((address_space(1))) unsigned int*)g,
      (__attribute__((address_space(3))) unsigned int*)l, 16, 0, 0);
}

// ============================================================================
// repack: K[b,s,h*64+e] f32 -> ws tiles bf16; V -> V^T tiles bf16.
// Tile (bh, sblk): bytes [0,8192) = K rows kv (128B each), 16B chunk c at
// kv*128 + ((c*16) ^ ((kv&7)<<4)); bytes [8192,16384) = V^T rows d, same swz.
// ============================================================================
__global__ __launch_bounds__(256) void repack_kv(const float* __restrict__ Kg,
                                                 const float* __restrict__ Vg,
                                                 unsigned char* __restrict__ ws)
{
  __shared__ __align__(16) unsigned short vlds[64 * 72];
  const int sblk = blockIdx.x, bh = blockIdx.y;
  const int b = bh >> 4, h = bh & 15;
  const int tid = threadIdx.x;
  const int row = tid >> 2;        // 0..63
  const int cq  = tid & 3;         // 16-elem chunk
  const int xr  = (row & 7) << 4;
  unsigned char* tile = ws + ((size_t)bh * NSBLK + sblk) * TILE_BYTES;

  // ---- K tile ----
  {
    const float* kp = Kg + ((size_t)b * SK + sblk * KVB + row) * 1024 + h * 64 + cq * 16;
    f32x4 a = *(const f32x4*)kp,       b4 = *(const f32x4*)(kp + 4);
    f32x4 c4 = *(const f32x4*)(kp + 8), d4 = *(const f32x4*)(kp + 12);
    *(bf16x8*)(tile + row * 128 + ((cq * 32) ^ xr))      = cvt8v(a, b4);
    *(bf16x8*)(tile + row * 128 + ((cq * 32 + 16) ^ xr)) = cvt8v(c4, d4);
  }
  // ---- V^T tile via LDS transpose ----
  {
    const float* vp = Vg + ((size_t)b * SK + sblk * KVB + row) * 1024 + h * 64 + cq * 16;
    f32x4 a = *(const f32x4*)vp,       b4 = *(const f32x4*)(vp + 4);
    f32x4 c4 = *(const f32x4*)(vp + 8), d4 = *(const f32x4*)(vp + 12);
    #pragma unroll
    for (int j = 0; j < 4; j++) {
      vlds[(cq * 16 + j) * 72 + row]      = __builtin_bit_cast(unsigned short, (bf16_t)a[j]);
      vlds[(cq * 16 + 4 + j) * 72 + row]  = __builtin_bit_cast(unsigned short, (bf16_t)b4[j]);
      vlds[(cq * 16 + 8 + j) * 72 + row]  = __builtin_bit_cast(unsigned short, (bf16_t)c4[j]);
      vlds[(cq * 16 + 12 + j) * 72 + row] = __builtin_bit_cast(unsigned short, (bf16_t)d4[j]);
    }
    __syncthreads();
    bf16x8 r0 = *(const bf16x8*)&vlds[row * 72 + cq * 16];
    bf16x8 r1 = *(const bf16x8*)&vlds[row * 72 + cq * 16 + 8];
    *(bf16x8*)(tile + 8192 + row * 128 + ((cq * 32) ^ xr))      = r0;
    *(bf16x8*)(tile + 8192 + row * 128 + ((cq * 32 + 16) ^ xr)) = r1;
  }
}

// ============================================================================
// main: DMA-staged double-buffered flash attention, 32x32x16 MFMA.
// ============================================================================
__global__ __launch_bounds__(256, 2)
void xattn2(const float* __restrict__ Qg, const float* __restrict__ Mg,
            const unsigned char* __restrict__ KV, float* __restrict__ Og)
{
  __shared__ __align__(16) unsigned char buf[2][TILE_BYTES];

  const int f   = blockIdx.x;
  const int xcd = f & 7, ii = f >> 3;
  const int bh  = (xcd << 3) + (ii >> 4);   // 8 bh per XCD
  const int lt  = ii & 15;
  const int b = bh >> 4, h = bh & 15;
  const int tid = threadIdx.x, w = tid >> 6, lane = tid & 63;
  const int q32 = lane & 31, hi = lane >> 5;
  const int qr0 = lt * QTILE + w * 32;
  const int xr  = (q32 & 7) << 4;

  // ---- Q B-frags, pre-scaled by (1/8)*log2(e) ----
  const float qs = 0.125f * 1.44269504088896340736f;
  bf16x8 qf[4];
  {
    const float* qp = Qg + ((size_t)b * LQ + qr0 + q32) * 1024 + h * 64 + hi * 8;
    #pragma unroll
    for (int ec = 0; ec < 4; ec++) {
      f32x4 x = *(const f32x4*)(qp + ec * 16);
      f32x4 y = *(const f32x4*)(qp + ec * 16 + 4);
      #pragma unroll
      for (int j = 0; j < 4; j++) { x[j] *= qs; y[j] *= qs; }
      qf[ec] = cvt8v(x, y);
    }
  }

  f32x16 acc0, acc1;
  #pragma unroll
  for (int m = 0; m < 16; m++) { acc0[m] = 0.f; acc1[m] = 0.f; }
  float mrun = -1e30f, zrun = 0.f;

  const unsigned char* gsrc = KV + (size_t)bh * NSBLK * TILE_BYTES + tid * 16;
  const float* mbase = Mg + (size_t)(qr0 + q32) * SK + hi * 4;

  // prologue: DMA tile 0 into buf[0]
  {
    unsigned char* l = &buf[0][w * 1024];
    #pragma unroll
    for (int r = 0; r < 4; r++) gll16(gsrc + r * 4096, l + r * 4096);
  }
  __syncthreads();

  for (int nt = 0; nt < NSBLK; ++nt) {
    const unsigned char* cur = buf[nt & 1];

    // issue DMA for next tile into the other buffer (drained at loop-end barrier)
    if (nt + 1 < NSBLK) {
      const unsigned char* s = gsrc + (size_t)(nt + 1) * TILE_BYTES;
      unsigned char* l = &buf[(nt + 1) & 1][w * 1024];
      #pragma unroll
      for (int r = 0; r < 4; r++) gll16(s + r * 4096, l + r * 4096);
    }

    // mask loads for THIS tile: mk[kvt*4+mq] covers kv = 32kvt+8mq+4hi+{0..3}
    f32x4 mk[8];
    {
      const float* mp = mbase + nt * KVB;
      #pragma unroll
      for (int kvt = 0; kvt < 2; kvt++)
        #pragma unroll
        for (int mq = 0; mq < 4; mq++)
          mk[kvt * 4 + mq] = *(const f32x4*)(mp + kvt * 32 + mq * 8);
    }

    // ---- QK^T swapped: sT[kvt] = S^T[kv 32-block][q32] ----
    f32x16 sT[2];
    #pragma unroll
    for (int m = 0; m < 16; m++) { sT[0][m] = 0.f; sT[1][m] = 0.f; }
    __builtin_amdgcn_s_setprio(1);
    #pragma unroll
    for (int ec = 0; ec < 4; ec++) {
      bf16x8 kf0 = *(const bf16x8*)(cur + q32 * 128 + ((ec * 32 + hi * 16) ^ xr));
      sT[0] = __builtin_amdgcn_mfma_f32_32x32x16_bf16(kf0, qf[ec], sT[0], 0, 0, 0);
      bf16x8 kf1 = *(const bf16x8*)(cur + (32 + q32) * 128 + ((ec * 32 + hi * 16) ^ xr));
      sT[1] = __builtin_amdgcn_mfma_f32_32x32x16_bf16(kf1, qf[ec], sT[1], 0, 0, 0);
    }
    __builtin_amdgcn_s_setprio(0);

    // ---- online softmax for q = q32 (tree-reduced max) ----
    float mx0 = fmaxf(fmaxf(sT[0][0], sT[0][4]), fmaxf(sT[0][8],  sT[0][12]));
    float mx1 = fmaxf(fmaxf(sT[0][1], sT[0][5]), fmaxf(sT[0][9],  sT[0][13]));
    float mx2 = fmaxf(fmaxf(sT[0][2], sT[0][6]), fmaxf(sT[0][10], sT[0][14]));
    float mx3 = fmaxf(fmaxf(sT[0][3], sT[0][7]), fmaxf(sT[0][11], sT[0][15]));
    mx0 = fmaxf(mx0, fmaxf(fmaxf(sT[1][0], sT[1][4]), fmaxf(sT[1][8],  sT[1][12])));
    mx1 = fmaxf(mx1, fmaxf(fmaxf(sT[1][1], sT[1][5]), fmaxf(sT[1][9],  sT[1][13])));
    mx2 = fmaxf(mx2, fmaxf(fmaxf(sT[1][2], sT[1][6]), fmaxf(sT[1][10], sT[1][14])));
    mx3 = fmaxf(mx3, fmaxf(fmaxf(sT[1][3], sT[1][7]), fmaxf(sT[1][11], sT[1][15])));
    float rmax = fmaxf(fmaxf(mx0, mx1), fmaxf(mx2, mx3));
    rmax = fmaxf(rmax, __shfl_xor(rmax, 32));

    if (!__all(rmax <= mrun + 6.0f)) {   // defer-rescale, P bounded by 2^6
      float nm = fmaxf(mrun, rmax);
      float corr = exp2f(mrun - nm);
      mrun = nm; zrun *= corr;
      #pragma unroll
      for (int m = 0; m < 16; m++) { acc0[m] *= corr; acc1[m] *= corr; }
    }

    float s0s = 0.f, s1s = 0.f;
    #pragma unroll
    for (int m = 0; m < 16; m++) { sT[0][m] = exp2f(sT[0][m] - mrun); s0s += sT[0][m]; }
    #pragma unroll
    for (int m = 0; m < 16; m++) { sT[1][m] = exp2f(sT[1][m] - mrun); s1s += sT[1][m]; }
    float rs = s0s + s1s;
    rs += __shfl_xor(rs, 32);
    zrun += rs;   // UNMASKED denominator

    // ---- post-softmax multiplicative mask into numerator ----
    #pragma unroll
    for (int kvt = 0; kvt < 2; kvt++)
      #pragma unroll
      for (int m = 0; m < 16; m++) sT[kvt][m] *= mk[kvt * 4 + (m >> 2)][m & 3];

    // ---- P -> PV B-frags in-register: cvt_pk + permlane32_swap ----
    bf16x8 pf[4];
    #pragma unroll
    for (int kvt = 0; kvt < 2; kvt++) {
      #pragma unroll
      for (int c = 0; c < 2; c++) {
        unsigned a0 = pk2(sT[kvt][8 * c + 0], sT[kvt][8 * c + 1]);
        unsigned a1 = pk2(sT[kvt][8 * c + 2], sT[kvt][8 * c + 3]);
        unsigned b0 = pk2(sT[kvt][8 * c + 4], sT[kvt][8 * c + 5]);
        unsigned b1 = pk2(sT[kvt][8 * c + 6], sT[kvt][8 * c + 7]);
        uint2v r02 = __builtin_amdgcn_permlane32_swap(a0, b0, false, false);
        uint2v r13 = __builtin_amdgcn_permlane32_swap(a1, b1, false, false);
        U4B8 u; u.u = uint4v{r02[0], r13[0], r02[1], r13[1]};
        pf[kvt * 2 + c] = u.v;
      }
    }

    // ---- PV swapped: acc += V^T x P^T ----
    __builtin_amdgcn_s_setprio(1);
    #pragma unroll
    for (int c = 0; c < 4; c++) {
      bf16x8 vf0 = *(const bf16x8*)(cur + 8192 + q32 * 128 + ((c * 32 + hi * 16) ^ xr));
      acc0 = __builtin_amdgcn_mfma_f32_32x32x16_bf16(vf0, pf[c], acc0, 0, 0, 0);
      bf16x8 vf1 = *(const bf16x8*)(cur + 8192 + (32 + q32) * 128 + ((c * 32 + hi * 16) ^ xr));
      acc1 = __builtin_amdgcn_mfma_f32_32x32x16_bf16(vf1, pf[c], acc1, 0, 0, 0);
    }
    __builtin_amdgcn_s_setprio(0);

    __syncthreads();  // drains next-tile DMA (vmcnt 0) + releases cur buffer
  }

  // ---- epilogue ----
  {
    float inv = 1.0f / zrun;
    float* op = Og + ((size_t)bh * LQ + qr0 + q32) * 64 + hi * 4;
    #pragma unroll
    for (int mq = 0; mq < 4; mq++) {
      f32x4 o0, o1;
      #pragma unroll
      for (int r = 0; r < 4; r++) { o0[r] = acc0[4 * mq + r] * inv; o1[r] = acc1[4 * mq + r] * inv; }
      *(f32x4*)(op + mq * 8) = o0;
      *(f32x4*)(op + 32 + mq * 8) = o1;
    }
  }
}

// ============================================================================
// fallback (R4 kernel) for small ws_size
// ============================================================================
__global__ __launch_bounds__(256, 2)
void xattn_fwd(const float* __restrict__ Qg, const float* __restrict__ Kg,
               const float* __restrict__ Vg, const float* __restrict__ Mg,
               float* __restrict__ Og)
{
  __shared__ __align__(16) unsigned short Kt[64 * KSTR];
  __shared__ __align__(16) unsigned short Vt[64 * KSTR];
  const int f   = blockIdx.x + blockIdx.y * gridDim.x;
  const int xcd = f & 7;
  const int ii  = f >> 3;
  const int bh  = (xcd << 3) + (ii >> 4);
  const int lt  = ii & 15;
  const int b = bh >> 4, h = bh & 15;
  const int tid  = threadIdx.x;
  const int w    = tid >> 6;
  const int lane = tid & 63;
  const int q32  = lane & 31;
  const int hi   = lane >> 5;
  const int qr0  = lt * QTILE + w * 32;
  const float qs = 0.125f * 1.44269504088896340736f;
  bf16x8 qf[4];
  {
    const float* qp = Qg + ((size_t)b * LQ + qr0 + q32) * 1024 + h * 64 + hi * 8;
    #pragma unroll
    for (int ec = 0; ec < 4; ec++) {
      f32x4 x = *(const f32x4*)(qp + ec * 16);
      f32x4 y = *(const f32x4*)(qp + ec * 16 + 4);
      #pragma unroll
      for (int j = 0; j < 4; j++) { x[j] *= qs; y[j] *= qs; }
      qf[ec] = cvt8v(x, y);
    }
  }
  f32x16 acc0, acc1;
  #pragma unroll
  for (int m = 0; m < 16; m++) { acc0[m] = 0.f; acc1[m] = 0.f; }
  float mrun = -1e30f, zrun = 0.f;
  const int kr = tid >> 2;
  const int kc = (tid & 3) << 4;
  const int vd = tid & 63;
  const int vk0 = w << 4;
  const float* kbase = Kg + (size_t)b * SK * 1024 + h * 64;
  const float* vbase = Vg + (size_t)b * SK * 1024 + h * 64;
  const float* mbase = Mg + (size_t)(qr0 + q32) * SK + hi * 4;
  f32x4 ka, kb, kc4, kd;
  float vr[16];
  {
    const float* kp = kbase + (size_t)kr * 1024 + kc;
    ka = *(const f32x4*)kp;        kb = *(const f32x4*)(kp + 4);
    kc4 = *(const f32x4*)(kp + 8); kd = *(const f32x4*)(kp + 12);
    const float* vp = vbase + (size_t)vk0 * 1024 + vd;
    #pragma unroll
    for (int j = 0; j < 16; j++) vr[j] = vp[(size_t)j * 1024];
  }
  for (int s0 = 0; s0 < SK; s0 += KVB) {
    bf16x8 kcv0 = cvt8v(ka, kb), kcv1 = cvt8v(kc4, kd);
    bf16x8 vcv0, vcv1;
    #pragma unroll
    for (int j = 0; j < 8; j++) { vcv0[j] = (bf16_t)vr[j]; vcv1[j] = (bf16_t)vr[8 + j]; }
    __syncthreads();
    *(bf16x8*)&Kt[kr * KSTR + kc] = kcv0;
    *(bf16x8*)&Kt[kr * KSTR + kc + 8] = kcv1;
    *(bf16x8*)&Vt[vd * KSTR + vk0] = vcv0;
    *(bf16x8*)&Vt[vd * KSTR + vk0 + 8] = vcv1;
    __syncthreads();
    f32x4 mk[8];
    {
      const float* mp = mbase + s0;
      #pragma unroll
      for (int kvt = 0; kvt < 2; kvt++)
        #pragma unroll
        for (int mq = 0; mq < 4; mq++)
          mk[kvt * 4 + mq] = *(const f32x4*)(mp + kvt * 32 + mq * 8);
    }
    if (s0 + KVB < SK) {
      const float* kp = kbase + (size_t)(s0 + KVB + kr) * 1024 + kc;
      ka = *(const f32x4*)kp;        kb = *(const f32x4*)(kp + 4);
      kc4 = *(const f32x4*)(kp + 8); kd = *(const f32x4*)(kp + 12);
      const float* vp = vbase + (size_t)(s0 + KVB + vk0) * 1024 + vd;
      #pragma unroll
      for (int j = 0; j < 16; j++) vr[j] = vp[(size_t)j * 1024];
    }
    f32x16 sT[2];
    #pragma unroll
    for (int m = 0; m < 16; m++) { sT[0][m] = 0.f; sT[1][m] = 0.f; }
    #pragma unroll
    for (int ec = 0; ec < 4; ec++) {
      bf16x8 kf0 = *(const bf16x8*)&Kt[q32 * KSTR + ec * 16 + hi * 8];
      sT[0] = __builtin_amdgcn_mfma_f32_32x32x16_bf16(kf0, qf[ec], sT[0], 0, 0, 0);
      bf16x8 kf1 = *(const bf16x8*)&Kt[(32 + q32) * KSTR + ec * 16 + hi * 8];
      sT[1] = __builtin_amdgcn_mfma_f32_32x32x16_bf16(kf1, qf[ec], sT[1], 0, 0, 0);
    }
    float rmax = sT[0][0];
    #pragma unroll
    for (int m = 1; m < 16; m++) rmax = fmaxf(rmax, sT[0][m]);
    #pragma unroll
    for (int m = 0; m < 16; m++) rmax = fmaxf(rmax, sT[1][m]);
    rmax = fmaxf(rmax, __shfl_xor(rmax, 32));
    if (!__all(rmax <= mrun + 6.0f)) {
      float nm = fmaxf(mrun, rmax);
      float corr = exp2f(mrun - nm);
      mrun = nm; zrun *= corr;
      #pragma unroll
      for (int m = 0; m < 16; m++) { acc0[m] *= corr; acc1[m] *= corr; }
    }
    float rs = 0.f;
    #pragma unroll
    for (int kvt = 0; kvt < 2; kvt++)
      #pragma unroll
      for (int m = 0; m < 16; m++) { sT[kvt][m] = exp2f(sT[kvt][m] - mrun); rs += sT[kvt][m]; }
    rs += __shfl_xor(rs, 32);
    zrun += rs;
    #pragma unroll
    for (int kvt = 0; kvt < 2; kvt++)
      #pragma unroll
      for (int m = 0; m < 16; m++) sT[kvt][m] *= mk[kvt * 4 + (m >> 2)][m & 3];
    bf16x8 pf[4];
    #pragma unroll
    for (int kvt = 0; kvt < 2; kvt++) {
      #pragma unroll
      for (int c = 0; c < 2; c++) {
        unsigned a0 = pk2(sT[kvt][8 * c + 0], sT[kvt][8 * c + 1]);
        unsigned a1 = pk2(sT[kvt][8 * c + 2], sT[kvt][8 * c + 3]);
        unsigned b0 = pk2(sT[kvt][8 * c + 4], sT[kvt][8 * c + 5]);
        unsigned b1 = pk2(sT[kvt][8 * c + 6], sT[kvt][8 * c + 7]);
        uint2v r02 = __builtin_amdgcn_permlane32_swap(a0, b0, false, false);
        uint2v r13 = __builtin_amdgcn_permlane32_swap(a1, b1, false, false);
        U4B8 u; u.u = uint4v{r02[0], r13[0], r02[1], r13[1]};
        pf[kvt * 2 + c] = u.v;
      }
    }
    #pragma unroll
    for (int c = 0; c < 4; c++) {
      bf16x8 vf0 = *(const bf16x8*)&Vt[q32 * KSTR + c * 16 + hi * 8];
      acc0 = __builtin_amdgcn_mfma_f32_32x32x16_bf16(vf0, pf[c], acc0, 0, 0, 0);
      bf16x8 vf1 = *(const bf16x8*)&Vt[(32 + q32) * KSTR + c * 16 + hi * 8];
      acc1 = __builtin_amdgcn_mfma_f32_32x32x16_bf16(vf1, pf[c], acc1, 0, 0, 0);
    }
  }
  {
    float inv = 1.0f / zrun;
    float* op = Og + ((size_t)bh * LQ + qr0 + q32) * 64 + hi * 4;
    #pragma unroll
    for (int mq = 0; mq < 4; mq++) {
      f32x4 o0, o1;
      #pragma unroll
      for (int r = 0; r < 4; r++) { o0[r] = acc0[4 * mq + r] * inv; o1[r] = acc1[4 * mq + r] * inv; }
      *(f32x4*)(op + mq * 8) = o0;
      *(f32x4*)(op + 32 + mq * 8) = o1;
    }
  }
}

extern "C" void kernel_launch(void* const* d_in, const int* in_sizes, int n_in,
                              void* d_out, int out_size, void* d_ws, size_t ws_size,
                              hipStream_t stream) {
  const float* Qg = (const float*)d_in[0];
  const float* Kg = (const float*)d_in[1];
  const float* Vg = (const float*)d_in[2];
  const float* Mg = (const float*)d_in[3];
  float* Og = (float*)d_out;
  if (ws_size >= WS_NEED) {
    repack_kv<<<dim3(NSBLK, 4 * NH), 256, 0, stream>>>(Kg, Vg, (unsigned char*)d_ws);
    xattn2<<<LQ / QTILE * 4 * NH, 256, 0, stream>>>(Qg, Mg, (const unsigned char*)d_ws, Og);
  } else {
    xattn_fwd<<<dim3(LQ / QTILE, 4 * NH), 256, 0, stream>>>(Qg, Kg, Vg, Mg, Og);
  }
}